// Round 6
// baseline (519.481 us; speedup 1.0000x reference)
//
#include <hip/hip_runtime.h>
#include <math.h>

#define N_NODES 16384
#define N_EDGES 32768
#define NGRAPH  512
#define DIM     64
#define NF      14
#define HIDN    128
#define EWCOLS  4096

typedef unsigned short u16;
typedef unsigned int   u32;
typedef __attribute__((ext_vector_type(8))) short bf16x8;
typedef __attribute__((ext_vector_type(4))) float f32x4;
typedef __attribute__((ext_vector_type(4))) u32   u32x4;

__device__ inline float b2f(u16 u){
    unsigned int x = ((unsigned int)u) << 16;
    return __builtin_bit_cast(float, x);
}
__device__ inline u16 f2b(float f){
    unsigned int x = __builtin_bit_cast(unsigned int, f);
    unsigned int r = (x + 0x7FFFu + ((x >> 16) & 1u)) >> 16;   // RNE
    return (u16)r;
}
__device__ inline float sigf(float x){ return 1.f / (1.f + expf(-x)); }

// out[n,f] = relu(x[n,:14] @ lin0_w + lin0_b)
__global__ __launch_bounds__(256) void k_lin0(const float* __restrict__ x,
        const float* __restrict__ w, const float* __restrict__ b, float* __restrict__ out){
    int n = (blockIdx.x * blockDim.x + threadIdx.x) >> 6;
    int lane = threadIdx.x & 63;
    if (n >= N_NODES) return;
    float xv = (lane < NF) ? x[n * NF + lane] : 0.f;
    float acc = b[lane];
    #pragma unroll
    for (int d = 0; d < NF; ++d){
        float xd = __shfl(xv, d);
        acc += xd * w[d * DIM + lane];
    }
    out[n * DIM + lane] = fmaxf(acc, 0.f);
}

// merged weight prep: w2T (bf16), LSTM transposes (fp32), GRU hi/lo splits (bf16)
__global__ __launch_bounds__(256) void k_prep(const float* __restrict__ w2,
        const float* __restrict__ lwih, const float* __restrict__ lwhh,
        const float* __restrict__ root, const float* __restrict__ gwih, const float* __restrict__ gwhh,
        u16* __restrict__ w2T, float* __restrict__ wihT, float* __restrict__ whhT,
        u16* __restrict__ rtHi, u16* __restrict__ rtLo,
        u16* __restrict__ wihHi, u16* __restrict__ wihLo,
        u16* __restrict__ whhHi, u16* __restrict__ whhLo){
    int i = blockIdx.x * 256 + threadIdx.x;
    if (i < 524288){
        int k = i >> 12, c = i & 4095;
        w2T[c * HIDN + k] = f2b(w2[i]);
    } else if (i < 557056){
        int i2 = i - 524288;
        int j = i2 >> 7, d = i2 & 127;
        wihT[d * 256 + j] = lwih[i2];
    } else if (i < 573440){
        int i2 = i - 557056;
        int j = i2 >> 6, d = i2 & 63;
        whhT[d * 256 + j] = lwhh[i2];
    } else if (i < 577536){
        int i2 = i - 573440;
        int d = i2 >> 6, j = i2 & 63;
        float v = root[i2]; u16 h = f2b(v);
        rtHi[j * 64 + d] = h; rtLo[j * 64 + d] = f2b(v - b2f(h));
    } else if (i < 589824){
        int k = i - 577536;
        float v = gwih[k]; u16 h = f2b(v);
        wihHi[k] = h; wihLo[k] = f2b(v - b2f(h));
    } else if (i < 602112){
        int k = i - 589824;
        float v = gwhh[k]; u16 h = f2b(v);
        whhHi[k] = h; whhLo[k] = f2b(v - b2f(h));
    }
}

__global__ __launch_bounds__(256) void k_deg(const int* __restrict__ ei, unsigned* __restrict__ degu){
    int e = blockIdx.x * blockDim.x + threadIdx.x;
    if (e < N_EDGES) atomicAdd(&degu[ei[N_EDGES + e]], 1u);
}
__global__ __launch_bounds__(256) void k_dinv(const unsigned* __restrict__ degu, float* __restrict__ dinv){
    int n = blockIdx.x * blockDim.x + threadIdx.x;
    if (n < N_NODES) dinv[n] = 1.f / fmaxf((float)degu[n], 1.f);
}

// ---------------------------------------------------------------------------
// Fused message kernel. EB=128 edges / 512 threads (8 waves).
// No B-panel LDS staging: W2T is 1 MB (L2-resident) -> direct global reads
// with register double-buffer prefetch. No barriers in the d-loop.
// ---------------------------------------------------------------------------
#define EB   128
#define LDO  68

__global__ __launch_bounds__(512) void k_msg_fused(
        const int* __restrict__ ei, const float* __restrict__ ea,
        const float* __restrict__ w1, const float* __restrict__ b1,
        const u16* __restrict__ w2T, const float* __restrict__ b2,
        const float* __restrict__ out, float* __restrict__ agg)
{
    __shared__ float s_out[EB * LDO];      // 34816 B
    __shared__ float s_b2[EWCOLS];         // 16384 B
    __shared__ float s_w1[512];
    __shared__ float s_b1[128];
    int tid = threadIdx.x;
    int e0 = blockIdx.x * EB;

    s_w1[tid] = w1[tid];
    if (tid < 128) s_b1[tid] = b1[tid];
    {
        int base = tid * 8;
        *(float4*)(s_b2 + base)     = *(const float4*)(b2 + base);
        *(float4*)(s_b2 + base + 4) = *(const float4*)(b2 + base + 4);
    }
    {
        int row = tid >> 2, cb = (tid & 3) * 16;
        int s = ei[e0 + row];
        const float4* sp = (const float4*)(out + (size_t)s * DIM + cb);
        float4 v0 = sp[0], v1 = sp[1], v2 = sp[2], v3 = sp[3];
        float* dst = s_out + row * LDO + cb;
        *(float4*)(dst)      = v0;
        *(float4*)(dst + 4)  = v1;
        *(float4*)(dst + 8)  = v2;
        *(float4*)(dst + 12) = v3;
    }
    __syncthreads();

    int wv = tid >> 6, lane = tid & 63;
    int WR = (wv >> 1) * 32, WC = (wv & 1) * 32;
    int lr = lane & 15, lk = (lane >> 4) * 8;
    int l16 = lane >> 4;

    // t A-fragments in registers: t[e,h] = relu(b1[h] + ea[e]·w1[:,h]), bf16
    bf16x8 afr[2][4];
    #pragma unroll
    for (int m = 0; m < 2; ++m){
        int erow = e0 + WR + m*16 + lr;
        float4 av = *(const float4*)(ea + (size_t)erow * 4);
        #pragma unroll
        for (int kk = 0; kk < 4; ++kk){
            bf16x8 t8;
            #pragma unroll
            for (int i = 0; i < 8; ++i){
                int h = kk*32 + lk + i;
                float acc = s_b1[h] + av.x*s_w1[h] + av.y*s_w1[128+h]
                          + av.z*s_w1[256+h] + av.w*s_w1[384+h];
                t8[i] = (short)f2b(fmaxf(acc, 0.f));
            }
            afr[m][kk] = t8;
        }
    }

    const u32x4* gb = (const u32x4*)w2T;
    int rowA = WC + lr;          // B col (frag 0)
    int rowB = WC + 16 + lr;     // B col (frag 1)
    int crow = (lane >> 4) * 4;
    f32x4 msg[2][2] = {};

    u32x4 fA[2][4], fB[2][4];    // register double buffer (static indices only)

#define LOADF(F, dd) { \
    int b0 = (((dd)*64 + rowA) << 4) + l16; \
    int b1i = (((dd)*64 + rowB) << 4) + l16; \
    F[0][0] = gb[b0];      F[0][1] = gb[b0 + 4]; \
    F[0][2] = gb[b0 + 8];  F[0][3] = gb[b0 + 12]; \
    F[1][0] = gb[b1i];     F[1][1] = gb[b1i + 4]; \
    F[1][2] = gb[b1i + 8]; F[1][3] = gb[b1i + 12]; }

#define COMPUTE(F, dd) { \
    f32x4 ew00 = {}, ew01 = {}, ew10 = {}, ew11 = {}; \
    _Pragma("unroll") \
    for (int kk = 0; kk < 4; ++kk){ \
        bf16x8 bf0 = __builtin_bit_cast(bf16x8, F[0][kk]); \
        bf16x8 bf1 = __builtin_bit_cast(bf16x8, F[1][kk]); \
        ew00 = __builtin_amdgcn_mfma_f32_16x16x32_bf16(afr[0][kk], bf0, ew00, 0, 0, 0); \
        ew01 = __builtin_amdgcn_mfma_f32_16x16x32_bf16(afr[0][kk], bf1, ew01, 0, 0, 0); \
        ew10 = __builtin_amdgcn_mfma_f32_16x16x32_bf16(afr[1][kk], bf0, ew10, 0, 0, 0); \
        ew11 = __builtin_amdgcn_mfma_f32_16x16x32_bf16(afr[1][kk], bf1, ew11, 0, 0, 0); \
    } \
    float b2v0 = s_b2[(dd)*64 + WC + lr]; \
    float b2v1 = s_b2[(dd)*64 + WC + 16 + lr]; \
    _Pragma("unroll") \
    for (int r = 0; r < 4; ++r){ \
        float sc0 = s_out[(WR + crow + r) * LDO + (dd)]; \
        float sc1 = s_out[(WR + 16 + crow + r) * LDO + (dd)]; \
        msg[0][0][r] += sc0 * (ew00[r] + b2v0); \
        msg[0][1][r] += sc0 * (ew01[r] + b2v1); \
        msg[1][0][r] += sc1 * (ew10[r] + b2v0); \
        msg[1][1][r] += sc1 * (ew11[r] + b2v1); \
    } }

    LOADF(fA, 0);
    for (int d = 0; d < 64; d += 2){
        LOADF(fB, d + 1);
        COMPUTE(fA, d);
        if (d + 2 < 64) LOADF(fA, d + 2);
        COMPUTE(fB, d + 1);
    }
#undef LOADF
#undef COMPUTE

    #pragma unroll
    for (int m = 0; m < 2; ++m){
        #pragma unroll
        for (int r = 0; r < 4; ++r){
            int eg = e0 + WR + m*16 + crow + r;
            int dn = ei[N_EDGES + eg];
            atomicAdd(&agg[(size_t)dn * DIM + WC + lr],      msg[m][0][r]);
            atomicAdd(&agg[(size_t)dn * DIM + WC + 16 + lr], msg[m][1][r]);
        }
    }
}

// ---------------------------------------------------------------------------
// k_update: MFMA with bf16x2 (hi+lo) precision splitting (unchanged, passing).
// ---------------------------------------------------------------------------
#define LDH 68
__global__ __launch_bounds__(256) void k_update(
        const u16* __restrict__ rtHi, const u16* __restrict__ rtLo,
        const u16* __restrict__ wihHi, const u16* __restrict__ wihLo,
        const u16* __restrict__ whhHi, const u16* __restrict__ whhLo,
        const float* __restrict__ convb, const float* __restrict__ bih,
        const float* __restrict__ bhh,
        const float* __restrict__ agg, const float* __restrict__ dinv,
        float* __restrict__ out)
{
    __shared__ float s_h[64 * LDH];
    __shared__ float s_aux[64 * LDH];
    __shared__ float s_m[64 * LDH];
    int tid = threadIdx.x;
    int n0 = blockIdx.x * 64;

    {
        int row = tid >> 2, cb = (tid & 3) * 16;
        const float4* hp = (const float4*)(out + (size_t)(n0 + row) * DIM + cb);
        const float4* ap = (const float4*)(agg + (size_t)(n0 + row) * DIM + cb);
        float di = dinv[n0 + row];
        #pragma unroll
        for (int q = 0; q < 4; ++q){
            float4 hv = hp[q];
            float4 av = ap[q];
            *(float4*)(s_h + row * LDH + cb + q*4) = hv;
            float4 xv;
            xv.x = av.x * di + convb[cb + q*4 + 0];
            xv.y = av.y * di + convb[cb + q*4 + 1];
            xv.z = av.z * di + convb[cb + q*4 + 2];
            xv.w = av.w * di + convb[cb + q*4 + 3];
            *(float4*)(s_aux + row * LDH + cb + q*4) = xv;
        }
    }
    __syncthreads();

    int wv = tid >> 6, lane = tid & 63;
    int lr = lane & 15, lkb = (lane >> 4) * 8;
    int arow = wv * 16 + lr;

    bf16x8 hHi[2], hLo[2];
    #pragma unroll
    for (int kk = 0; kk < 2; ++kk){
        const float* src = s_h + arow * LDH + kk*32 + lkb;
        bf16x8 hi8, lo8;
        #pragma unroll
        for (int e = 0; e < 8; ++e){
            float v = src[e];
            u16 h = f2b(v);
            hi8[e] = (short)h;
            lo8[e] = (short)f2b(v - b2f(h));
        }
        hHi[kk] = hi8; hLo[kk] = lo8;
    }

    f32x4 c1[4] = {};
    #pragma unroll
    for (int ct = 0; ct < 4; ++ct){
        #pragma unroll
        for (int kk = 0; kk < 2; ++kk){
            int off = (ct*16 + lr) * 64 + kk*32 + lkb;
            bf16x8 bHi = *(const bf16x8*)(rtHi + off);
            bf16x8 bLo = *(const bf16x8*)(rtLo + off);
            c1[ct] = __builtin_amdgcn_mfma_f32_16x16x32_bf16(hHi[kk], bHi, c1[ct], 0, 0, 0);
            c1[ct] = __builtin_amdgcn_mfma_f32_16x16x32_bf16(hLo[kk], bHi, c1[ct], 0, 0, 0);
            c1[ct] = __builtin_amdgcn_mfma_f32_16x16x32_bf16(hHi[kk], bLo, c1[ct], 0, 0, 0);
        }
    }

    int crow = (lane >> 4) * 4;
    #pragma unroll
    for (int ct = 0; ct < 4; ++ct){
        #pragma unroll
        for (int r = 0; r < 4; ++r){
            int row = wv*16 + crow + r;
            int col = ct*16 + lr;
            float m = fmaxf(c1[ct][r] + s_aux[row * LDH + col], 0.f);
            s_m[row * LDH + col] = m;
        }
    }
    __syncthreads();

    bf16x8 mHi[2], mLo[2];
    #pragma unroll
    for (int kk = 0; kk < 2; ++kk){
        const float* src = s_m + arow * LDH + kk*32 + lkb;
        bf16x8 hi8, lo8;
        #pragma unroll
        for (int e = 0; e < 8; ++e){
            float v = src[e];
            u16 h = f2b(v);
            hi8[e] = (short)h;
            lo8[e] = (short)f2b(v - b2f(h));
        }
        mHi[kk] = hi8; mLo[kk] = lo8;
    }

    f32x4 gi[12] = {}, gh[12] = {};
    #pragma unroll
    for (int ct = 0; ct < 12; ++ct){
        #pragma unroll
        for (int kk = 0; kk < 2; ++kk){
            int off = (ct*16 + lr) * 64 + kk*32 + lkb;
            bf16x8 biH = *(const bf16x8*)(wihHi + off);
            bf16x8 biL = *(const bf16x8*)(wihLo + off);
            gi[ct] = __builtin_amdgcn_mfma_f32_16x16x32_bf16(mHi[kk], biH, gi[ct], 0, 0, 0);
            gi[ct] = __builtin_amdgcn_mfma_f32_16x16x32_bf16(mLo[kk], biH, gi[ct], 0, 0, 0);
            gi[ct] = __builtin_amdgcn_mfma_f32_16x16x32_bf16(mHi[kk], biL, gi[ct], 0, 0, 0);
            bf16x8 bhH = *(const bf16x8*)(whhHi + off);
            bf16x8 bhL = *(const bf16x8*)(whhLo + off);
            gh[ct] = __builtin_amdgcn_mfma_f32_16x16x32_bf16(hHi[kk], bhH, gh[ct], 0, 0, 0);
            gh[ct] = __builtin_amdgcn_mfma_f32_16x16x32_bf16(hLo[kk], bhH, gh[ct], 0, 0, 0);
            gh[ct] = __builtin_amdgcn_mfma_f32_16x16x32_bf16(hHi[kk], bhL, gh[ct], 0, 0, 0);
        }
    }

    #pragma unroll
    for (int ct = 0; ct < 4; ++ct){
        int col = ct*16 + lr;
        float br_i = bih[col],       br_h = bhh[col];
        float bz_i = bih[64 + col],  bz_h = bhh[64 + col];
        float bn_i = bih[128 + col], bn_h = bhh[128 + col];
        #pragma unroll
        for (int r = 0; r < 4; ++r){
            int row = wv*16 + crow + r;
            float rg = sigf(gi[ct][r] + br_i + gh[ct][r] + br_h);
            float zg = sigf(gi[ct+4][r] + bz_i + gh[ct+4][r] + bz_h);
            float ng = tanhf(gi[ct+8][r] + bn_i + rg * (gh[ct+8][r] + bn_h));
            float h  = s_h[row * LDH + col];
            s_aux[row * LDH + col] = (1.f - zg) * ng + zg * h;
        }
    }
    __syncthreads();

    {
        int row = tid >> 2, cb = (tid & 3) * 16;
        #pragma unroll
        for (int q = 0; q < 4; ++q)
            *(float4*)(out + (size_t)(n0 + row) * DIM + cb + q*4) =
                *(const float4*)(s_aux + row * LDH + cb + q*4);
    }
}

// ---------------------------------------------------------------------------
// Fully fused Set2Set (3 steps) + final MLP. One block per graph.
// ---------------------------------------------------------------------------
__global__ __launch_bounds__(256) void k_s2s(
        const float* __restrict__ out, const int* __restrict__ batch,
        const float* __restrict__ wihT, const float* __restrict__ lbih,
        const float* __restrict__ whhT, const float* __restrict__ lbhh,
        const float* __restrict__ l1w, const float* __restrict__ l1b,
        const float* __restrict__ l2w, const float* __restrict__ l2b,
        float* __restrict__ y)
{
    __shared__ float s_q[128];
    __shared__ float s_hc[128];
    __shared__ float s_g[256];
    __shared__ float s_rw[256];
    __shared__ float s_sw[8];
    __shared__ int   s_rng[2];
    int g = blockIdx.x, tid = threadIdx.x;
    if (tid < 2){
        int target = g + tid;
        int lo = 0, hi = N_NODES;
        while (lo < hi){ int mid = (lo + hi) >> 1; if (batch[mid] < target) lo = mid + 1; else hi = mid; }
        s_rng[tid] = lo;
    }
    if (tid < 128){ s_q[tid] = 0.f; s_hc[tid] = 0.f; }
    __syncthreads();
    int s0 = s_rng[0], s1 = s_rng[1];
    int wv = tid >> 6, lane = tid & 63;

    for (int step = 0; step < 3; ++step){
        float acc = lbih[tid] + lbhh[tid];
        #pragma unroll 8
        for (int d = 0; d < 128; ++d) acc += s_q[d] * wihT[d * 256 + tid];
        #pragma unroll 8
        for (int d = 0; d < 64;  ++d) acc += s_hc[d] * whhT[d * 256 + tid];
        s_g[tid] = acc;
        __syncthreads();
        if (tid < 64){
            float c = sigf(s_g[64 + tid]) * s_hc[64 + tid] + sigf(s_g[tid]) * tanhf(s_g[128 + tid]);
            float h = sigf(s_g[192 + tid]) * tanhf(c);
            s_hc[tid] = h; s_hc[64 + tid] = c;
            s_q[tid] = h;
        }
        __syncthreads();
        float q = s_hc[lane];
        float emx = -3.4e38f;
        for (int n = s0 + wv; n < s1; n += 4){
            float v = out[(size_t)n * DIM + lane] * q;
            #pragma unroll
            for (int off = 32; off; off >>= 1) v += __shfl_xor(v, off);
            emx = fmaxf(emx, v);
        }
        if (lane == 0) s_sw[wv] = emx;
        __syncthreads();
        float gmax = fmaxf(fmaxf(s_sw[0], s_sw[1]), fmaxf(s_sw[2], s_sw[3]));
        float rl = 0.f, ss = 0.f;
        for (int n = s0 + wv; n < s1; n += 4){
            float o = out[(size_t)n * DIM + lane];
            float v = o * q;
            #pragma unroll
            for (int off = 32; off; off >>= 1) v += __shfl_xor(v, off);
            float ex = expf(v - gmax);
            rl += ex * o;
            ss += ex;
        }
        s_rw[wv * 64 + lane] = rl;
        if (lane == 0) s_sw[4 + wv] = ss;
        __syncthreads();
        if (tid < 64){
            float r = s_rw[tid] + s_rw[64 + tid] + s_rw[128 + tid] + s_rw[192 + tid];
            float S = fmaxf(s_sw[4] + s_sw[5] + s_sw[6] + s_sw[7], 1e-16f);
            s_q[64 + tid] = r / S;
        }
        __syncthreads();
    }
    if (wv == 0){
        float acc = l1b[lane];
        #pragma unroll 8
        for (int d = 0; d < 128; ++d) acc += s_q[d] * l1w[d * 64 + lane];
        float h = fmaxf(acc, 0.f);
        float p = h * l2w[lane];
        #pragma unroll
        for (int off = 32; off; off >>= 1) p += __shfl_down(p, off);
        if (lane == 0) y[g] = p + l2b[0];
    }
}

extern "C" void kernel_launch(void* const* d_in, const int* in_sizes, int n_in,
                              void* d_out, int out_size, void* d_ws, size_t ws_size,
                              hipStream_t stream){
    const float* x      = (const float*)d_in[0];
    const int*   ei     = (const int*)d_in[1];
    const float* ea     = (const float*)d_in[2];
    const int*   batch  = (const int*)d_in[3];
    const float* lin0_w = (const float*)d_in[6];
    const float* lin0_b = (const float*)d_in[7];
    const float* nn1_w  = (const float*)d_in[8];
    const float* nn1_b  = (const float*)d_in[9];
    const float* nn2_w  = (const float*)d_in[10];
    const float* nn2_b  = (const float*)d_in[11];
    const float* root_w = (const float*)d_in[12];
    const float* conv_b = (const float*)d_in[13];
    const float* gwih   = (const float*)d_in[14];
    const float* gwhh   = (const float*)d_in[15];
    const float* gbih   = (const float*)d_in[16];
    const float* gbhh   = (const float*)d_in[17];
    const float* lwih   = (const float*)d_in[18];
    const float* lwhh   = (const float*)d_in[19];
    const float* lbih   = (const float*)d_in[20];
    const float* lbhh   = (const float*)d_in[21];
    const float* l1w    = (const float*)d_in[22];
    const float* l1b    = (const float*)d_in[23];
    const float* l2w    = (const float*)d_in[24];
    const float* l2b    = (const float*)d_in[25];
    float* y = (float*)d_out;

    char* p = (char*)d_ws;
    float* out   = (float*)p;    p += (size_t)N_NODES * DIM * 4;
    float* agg   = (float*)p;    p += (size_t)N_NODES * DIM * 4;
    u16* w2T     = (u16*)p;      p += (size_t)EWCOLS * HIDN * 2;
    float* wihT  = (float*)p;    p += 128 * 256 * 4;
    float* whhT  = (float*)p;    p += 64 * 256 * 4;
    u16* rtHi    = (u16*)p;      p += 4096 * 2;
    u16* rtLo    = (u16*)p;      p += 4096 * 2;
    u16* wihHi   = (u16*)p;      p += 12288 * 2;
    u16* wihLo   = (u16*)p;      p += 12288 * 2;
    u16* whhHi   = (u16*)p;      p += 12288 * 2;
    u16* whhLo   = (u16*)p;      p += 12288 * 2;
    unsigned* degu = (unsigned*)p; p += N_NODES * 4;
    float* dinv  = (float*)p;    p += N_NODES * 4;

    if ((size_t)(p - (char*)d_ws) > ws_size) return;

    hipMemsetAsync(degu, 0, N_NODES * 4, stream);

    k_prep<<<2352, 256, 0, stream>>>(nn2_w, lwih, lwhh, root_w, gwih, gwhh,
                w2T, wihT, whhT, rtHi, rtLo, wihHi, wihLo, whhHi, whhLo);
    k_lin0<<<N_NODES / 4, 256, 0, stream>>>(x, lin0_w, lin0_b, out);
    k_deg <<<N_EDGES / 256, 256, 0, stream>>>(ei, degu);
    k_dinv<<<N_NODES / 256, 256, 0, stream>>>(degu, dinv);

    for (int r = 0; r < 3; ++r){
        hipMemsetAsync(agg, 0, (size_t)N_NODES * DIM * 4, stream);
        k_msg_fused<<<N_EDGES / EB, 512, 0, stream>>>(ei, ea, nn1_w, nn1_b, w2T, nn2_b, out, agg);
        k_update   <<<N_NODES / 64, 256, 0, stream>>>(rtHi, rtLo, wihHi, wihLo, whhHi, whhLo,
                        conv_b, gbih, gbhh, agg, dinv, out);
    }

    k_s2s<<<NGRAPH, 256, 0, stream>>>(out, batch, wihT, lbih, whhT, lbhh,
                l1w, l1b, l2w, l2b, y);
}

// Round 7
// 321.673 us; speedup vs baseline: 1.6149x; 1.6149x over previous
//
#include <hip/hip_runtime.h>
#include <math.h>

#define N_NODES 16384
#define N_EDGES 32768
#define NGRAPH  512
#define DIM     64
#define NF      14
#define HIDN    128
#define EWCOLS  4096

typedef unsigned short u16;
typedef unsigned int   u32;
typedef __attribute__((ext_vector_type(8))) short bf16x8;
typedef __attribute__((ext_vector_type(4))) float f32x4;
typedef __attribute__((ext_vector_type(4))) u32   u32x4;

__device__ inline float b2f(u16 u){
    unsigned int x = ((unsigned int)u) << 16;
    return __builtin_bit_cast(float, x);
}
__device__ inline u16 f2b(float f){
    unsigned int x = __builtin_bit_cast(unsigned int, f);
    unsigned int r = (x + 0x7FFFu + ((x >> 16) & 1u)) >> 16;   // RNE
    return (u16)r;
}
__device__ inline float sigf(float x){ return 1.f / (1.f + expf(-x)); }

// out[n,f] = relu(x[n,:14] @ lin0_w + lin0_b)
__global__ __launch_bounds__(256) void k_lin0(const float* __restrict__ x,
        const float* __restrict__ w, const float* __restrict__ b, float* __restrict__ out){
    int n = (blockIdx.x * blockDim.x + threadIdx.x) >> 6;
    int lane = threadIdx.x & 63;
    if (n >= N_NODES) return;
    float xv = (lane < NF) ? x[n * NF + lane] : 0.f;
    float acc = b[lane];
    #pragma unroll
    for (int d = 0; d < NF; ++d){
        float xd = __shfl(xv, d);
        acc += xd * w[d * DIM + lane];
    }
    out[n * DIM + lane] = fmaxf(acc, 0.f);
}

// merged weight prep: w2T (bf16), LSTM transposes (fp32), GRU hi/lo splits (bf16)
__global__ __launch_bounds__(256) void k_prep(const float* __restrict__ w2,
        const float* __restrict__ lwih, const float* __restrict__ lwhh,
        const float* __restrict__ root, const float* __restrict__ gwih, const float* __restrict__ gwhh,
        u16* __restrict__ w2T, float* __restrict__ wihT, float* __restrict__ whhT,
        u16* __restrict__ rtHi, u16* __restrict__ rtLo,
        u16* __restrict__ wihHi, u16* __restrict__ wihLo,
        u16* __restrict__ whhHi, u16* __restrict__ whhLo){
    int i = blockIdx.x * 256 + threadIdx.x;
    if (i < 524288){
        int k = i >> 12, c = i & 4095;
        w2T[c * HIDN + k] = f2b(w2[i]);
    } else if (i < 557056){
        int i2 = i - 524288;
        int j = i2 >> 7, d = i2 & 127;
        wihT[d * 256 + j] = lwih[i2];
    } else if (i < 573440){
        int i2 = i - 557056;
        int j = i2 >> 6, d = i2 & 63;
        whhT[d * 256 + j] = lwhh[i2];
    } else if (i < 577536){
        int i2 = i - 573440;
        int d = i2 >> 6, j = i2 & 63;
        float v = root[i2]; u16 h = f2b(v);
        rtHi[j * 64 + d] = h; rtLo[j * 64 + d] = f2b(v - b2f(h));
    } else if (i < 589824){
        int k = i - 577536;
        float v = gwih[k]; u16 h = f2b(v);
        wihHi[k] = h; wihLo[k] = f2b(v - b2f(h));
    } else if (i < 602112){
        int k = i - 589824;
        float v = gwhh[k]; u16 h = f2b(v);
        whhHi[k] = h; whhLo[k] = f2b(v - b2f(h));
    }
}

__global__ __launch_bounds__(256) void k_deg(const int* __restrict__ ei, unsigned* __restrict__ degu){
    int e = blockIdx.x * blockDim.x + threadIdx.x;
    if (e < N_EDGES) atomicAdd(&degu[ei[N_EDGES + e]], 1u);
}
__global__ __launch_bounds__(256) void k_dinv(const unsigned* __restrict__ degu, float* __restrict__ dinv){
    int n = blockIdx.x * blockDim.x + threadIdx.x;
    if (n < N_NODES) dinv[n] = 1.f / fmaxf((float)degu[n], 1.f);
}

// ---------------------------------------------------------------------------
// Fused message kernel. EB=128 edges / 512 threads (8 waves).
// Raw s_barrier + manual lgkmcnt(0): B-panel prefetch (global loads) stays in
// flight across the barrier (no vmcnt(0) drain). b2 folded after the d-loop.
// LDS 70 KB -> 2 blocks/CU.
// ---------------------------------------------------------------------------
#define EB   128
#define LDO  68

__global__ __launch_bounds__(512) void k_msg_fused(
        const int* __restrict__ ei, const float* __restrict__ ea,
        const float* __restrict__ w1, const float* __restrict__ b1,
        const u16* __restrict__ w2T, const float* __restrict__ b2,
        const float* __restrict__ out, float* __restrict__ agg)
{
    __shared__ float s_out[EB * LDO];      // 34816 B
    __shared__ u16   s_b[2][64 * 128];     // 32768 B
    __shared__ float s_w1[512];
    __shared__ float s_b1[128];
    int tid = threadIdx.x;
    int e0 = blockIdx.x * EB;

    // B staging ids + prologue load (d=0) — issued first, in flight during setup
    int bc = tid >> 3, bs = tid & 7;
    const u32x4* gb = (const u32x4*)w2T;
    u32x4 r0 = gb[((size_t)bc << 4) + bs*2];
    u32x4 r1 = gb[((size_t)bc << 4) + bs*2 + 1];

    s_w1[tid] = w1[tid];
    if (tid < 128) s_b1[tid] = b1[tid];
    {
        int row = tid >> 2, cb = (tid & 3) * 16;
        int s = ei[e0 + row];
        const float4* sp = (const float4*)(out + (size_t)s * DIM + cb);
        float4 v0 = sp[0], v1 = sp[1], v2 = sp[2], v3 = sp[3];
        float* dst = s_out + row * LDO + cb;
        *(float4*)(dst)      = v0;
        *(float4*)(dst + 4)  = v1;
        *(float4*)(dst + 8)  = v2;
        *(float4*)(dst + 12) = v3;
    }
    __syncthreads();

    int wv = tid >> 6, lane = tid & 63;
    int WR = (wv >> 1) * 32, WC = (wv & 1) * 32;
    int lr = lane & 15, lk = (lane >> 4) * 8;

    // t A-fragments in registers: t[e,h] = relu(b1[h] + ea[e]·w1[:,h]), bf16
    bf16x8 afr[2][4];
    #pragma unroll
    for (int m = 0; m < 2; ++m){
        int erow = e0 + WR + m*16 + lr;
        float4 av = *(const float4*)(ea + (size_t)erow * 4);
        #pragma unroll
        for (int kk = 0; kk < 4; ++kk){
            bf16x8 t8;
            #pragma unroll
            for (int i = 0; i < 8; ++i){
                int h = kk*32 + lk + i;
                float acc = s_b1[h] + av.x*s_w1[h] + av.y*s_w1[128+h]
                          + av.z*s_w1[256+h] + av.w*s_w1[384+h];
                t8[i] = (short)f2b(fmaxf(acc, 0.f));
            }
            afr[m][kk] = t8;
        }
    }

    int swzw = (bc & 7) << 4;
    int swzr = (lr & 7) << 4;
    int crow = (lane >> 4) * 4;

    // write buf0 (d=0), issue loads for d=1
    {
        char* sw = (char*)s_b[0];
        *(u32x4*)(sw + ((bc*256 + bs*32)      ^ swzw)) = r0;
        *(u32x4*)(sw + ((bc*256 + bs*32 + 16) ^ swzw)) = r1;
        size_t base = ((size_t)64 + bc) << 4;
        r0 = gb[base + bs*2];
        r1 = gb[base + bs*2 + 1];
    }
    asm volatile("s_waitcnt lgkmcnt(0)" ::: "memory");
    __builtin_amdgcn_sched_barrier(0);
    __builtin_amdgcn_s_barrier();
    __builtin_amdgcn_sched_barrier(0);

    f32x4 msg[2][2] = {};

    for (int d = 0; d < 64; ++d){
        // stage buf[(d+1)&1] with regs (data d+1); issue loads for d+2.
        // Safe: buf[(d+1)&1] was last READ at iter d-1; the iter-(d-1) barrier
        // (with lgkmcnt(0) on reads) separates. Global loads for d+2 stay in
        // flight across this iteration's barrier (raw s_barrier, no vm drain).
        if (d < 63){
            char* sw = (char*)s_b[(d + 1) & 1];
            *(u32x4*)(sw + ((bc*256 + bs*32)      ^ swzw)) = r0;
            *(u32x4*)(sw + ((bc*256 + bs*32 + 16) ^ swzw)) = r1;
            if (d < 62){
                size_t base = ((size_t)(d + 2) * 64 + bc) << 4;
                r0 = gb[base + bs*2];
                r1 = gb[base + bs*2 + 1];
            }
        }
        // compute on buf[d&1]
        const char* sr = (const char*)s_b[d & 1];
        f32x4 ew00 = {}, ew01 = {}, ew10 = {}, ew11 = {};
        #pragma unroll
        for (int kk = 0; kk < 4; ++kk){
            int kb = kk*64 + (lane >> 4) * 16;
            bf16x8 bf0 = *(const bf16x8*)(sr + (((WC + lr)*256 + kb)      ^ swzr));
            bf16x8 bf1 = *(const bf16x8*)(sr + (((WC + 16 + lr)*256 + kb) ^ swzr));
            ew00 = __builtin_amdgcn_mfma_f32_16x16x32_bf16(afr[0][kk], bf0, ew00, 0, 0, 0);
            ew01 = __builtin_amdgcn_mfma_f32_16x16x32_bf16(afr[0][kk], bf1, ew01, 0, 0, 0);
            ew10 = __builtin_amdgcn_mfma_f32_16x16x32_bf16(afr[1][kk], bf0, ew10, 0, 0, 0);
            ew11 = __builtin_amdgcn_mfma_f32_16x16x32_bf16(afr[1][kk], bf1, ew11, 0, 0, 0);
        }
        #pragma unroll
        for (int r = 0; r < 4; ++r){
            float sc0 = s_out[(WR + crow + r) * LDO + d];
            float sc1 = s_out[(WR + 16 + crow + r) * LDO + d];
            msg[0][0][r] += sc0 * ew00[r];
            msg[0][1][r] += sc0 * ew01[r];
            msg[1][0][r] += sc1 * ew10[r];
            msg[1][1][r] += sc1 * ew11[r];
        }
        // all my LDS ops (ds_write of next buf + ds_reads of cur) complete,
        // then workgroup barrier. Prefetch vmem stays outstanding.
        asm volatile("s_waitcnt lgkmcnt(0)" ::: "memory");
        __builtin_amdgcn_sched_barrier(0);
        __builtin_amdgcn_s_barrier();
        __builtin_amdgcn_sched_barrier(0);
    }

    // fold the b2 term: msg += sum_d sc_d * b2[d*64 + f]
    int f0 = WC + lr;
    #pragma unroll 8
    for (int dd = 0; dd < 64; ++dd){
        float bv0 = b2[dd*64 + f0];
        float bv1 = b2[dd*64 + f0 + 16];
        #pragma unroll
        for (int r = 0; r < 4; ++r){
            float sc0 = s_out[(WR + crow + r) * LDO + dd];
            float sc1 = s_out[(WR + 16 + crow + r) * LDO + dd];
            msg[0][0][r] += sc0 * bv0;
            msg[0][1][r] += sc0 * bv1;
            msg[1][0][r] += sc1 * bv0;
            msg[1][1][r] += sc1 * bv1;
        }
    }

    #pragma unroll
    for (int m = 0; m < 2; ++m){
        #pragma unroll
        for (int r = 0; r < 4; ++r){
            int eg = e0 + WR + m*16 + crow + r;
            int dn = ei[N_EDGES + eg];
            atomicAdd(&agg[(size_t)dn * DIM + WC + lr],      msg[m][0][r]);
            atomicAdd(&agg[(size_t)dn * DIM + WC + 16 + lr], msg[m][1][r]);
        }
    }
}

// ---------------------------------------------------------------------------
// k_update: MFMA with bf16x2 (hi+lo) precision splitting. Now also zeroes agg
// after reading it (arms the next round / next graph replay; removes memsets).
// ---------------------------------------------------------------------------
#define LDH 68
__global__ __launch_bounds__(256) void k_update(
        const u16* __restrict__ rtHi, const u16* __restrict__ rtLo,
        const u16* __restrict__ wihHi, const u16* __restrict__ wihLo,
        const u16* __restrict__ whhHi, const u16* __restrict__ whhLo,
        const float* __restrict__ convb, const float* __restrict__ bih,
        const float* __restrict__ bhh,
        float* __restrict__ agg, const float* __restrict__ dinv,
        float* __restrict__ out)
{
    __shared__ float s_h[64 * LDH];
    __shared__ float s_aux[64 * LDH];
    __shared__ float s_m[64 * LDH];
    int tid = threadIdx.x;
    int n0 = blockIdx.x * 64;

    {
        int row = tid >> 2, cb = (tid & 3) * 16;
        const float4* hp = (const float4*)(out + (size_t)(n0 + row) * DIM + cb);
        float4* ap = (float4*)(agg + (size_t)(n0 + row) * DIM + cb);
        float di = dinv[n0 + row];
        float4 zv = {0.f, 0.f, 0.f, 0.f};
        #pragma unroll
        for (int q = 0; q < 4; ++q){
            float4 hv = hp[q];
            float4 av = ap[q];
            ap[q] = zv;                       // zero for next round / replay
            *(float4*)(s_h + row * LDH + cb + q*4) = hv;
            float4 xv;
            xv.x = av.x * di + convb[cb + q*4 + 0];
            xv.y = av.y * di + convb[cb + q*4 + 1];
            xv.z = av.z * di + convb[cb + q*4 + 2];
            xv.w = av.w * di + convb[cb + q*4 + 3];
            *(float4*)(s_aux + row * LDH + cb + q*4) = xv;
        }
    }
    __syncthreads();

    int wv = tid >> 6, lane = tid & 63;
    int lr = lane & 15, lkb = (lane >> 4) * 8;
    int arow = wv * 16 + lr;

    bf16x8 hHi[2], hLo[2];
    #pragma unroll
    for (int kk = 0; kk < 2; ++kk){
        const float* src = s_h + arow * LDH + kk*32 + lkb;
        bf16x8 hi8, lo8;
        #pragma unroll
        for (int e = 0; e < 8; ++e){
            float v = src[e];
            u16 h = f2b(v);
            hi8[e] = (short)h;
            lo8[e] = (short)f2b(v - b2f(h));
        }
        hHi[kk] = hi8; hLo[kk] = lo8;
    }

    f32x4 c1[4] = {};
    #pragma unroll
    for (int ct = 0; ct < 4; ++ct){
        #pragma unroll
        for (int kk = 0; kk < 2; ++kk){
            int off = (ct*16 + lr) * 64 + kk*32 + lkb;
            bf16x8 bHi = *(const bf16x8*)(rtHi + off);
            bf16x8 bLo = *(const bf16x8*)(rtLo + off);
            c1[ct] = __builtin_amdgcn_mfma_f32_16x16x32_bf16(hHi[kk], bHi, c1[ct], 0, 0, 0);
            c1[ct] = __builtin_amdgcn_mfma_f32_16x16x32_bf16(hLo[kk], bHi, c1[ct], 0, 0, 0);
            c1[ct] = __builtin_amdgcn_mfma_f32_16x16x32_bf16(hHi[kk], bLo, c1[ct], 0, 0, 0);
        }
    }

    int crow = (lane >> 4) * 4;
    #pragma unroll
    for (int ct = 0; ct < 4; ++ct){
        #pragma unroll
        for (int r = 0; r < 4; ++r){
            int row = wv*16 + crow + r;
            int col = ct*16 + lr;
            float m = fmaxf(c1[ct][r] + s_aux[row * LDH + col], 0.f);
            s_m[row * LDH + col] = m;
        }
    }
    __syncthreads();

    bf16x8 mHi[2], mLo[2];
    #pragma unroll
    for (int kk = 0; kk < 2; ++kk){
        const float* src = s_m + arow * LDH + kk*32 + lkb;
        bf16x8 hi8, lo8;
        #pragma unroll
        for (int e = 0; e < 8; ++e){
            float v = src[e];
            u16 h = f2b(v);
            hi8[e] = (short)h;
            lo8[e] = (short)f2b(v - b2f(h));
        }
        mHi[kk] = hi8; mLo[kk] = lo8;
    }

    f32x4 gi[12] = {}, gh[12] = {};
    #pragma unroll
    for (int ct = 0; ct < 12; ++ct){
        #pragma unroll
        for (int kk = 0; kk < 2; ++kk){
            int off = (ct*16 + lr) * 64 + kk*32 + lkb;
            bf16x8 biH = *(const bf16x8*)(wihHi + off);
            bf16x8 biL = *(const bf16x8*)(wihLo + off);
            gi[ct] = __builtin_amdgcn_mfma_f32_16x16x32_bf16(mHi[kk], biH, gi[ct], 0, 0, 0);
            gi[ct] = __builtin_amdgcn_mfma_f32_16x16x32_bf16(mLo[kk], biH, gi[ct], 0, 0, 0);
            gi[ct] = __builtin_amdgcn_mfma_f32_16x16x32_bf16(mHi[kk], biL, gi[ct], 0, 0, 0);
            bf16x8 bhH = *(const bf16x8*)(whhHi + off);
            bf16x8 bhL = *(const bf16x8*)(whhLo + off);
            gh[ct] = __builtin_amdgcn_mfma_f32_16x16x32_bf16(hHi[kk], bhH, gh[ct], 0, 0, 0);
            gh[ct] = __builtin_amdgcn_mfma_f32_16x16x32_bf16(hLo[kk], bhH, gh[ct], 0, 0, 0);
            gh[ct] = __builtin_amdgcn_mfma_f32_16x16x32_bf16(hHi[kk], bhL, gh[ct], 0, 0, 0);
        }
    }

    #pragma unroll
    for (int ct = 0; ct < 4; ++ct){
        int col = ct*16 + lr;
        float br_i = bih[col],       br_h = bhh[col];
        float bz_i = bih[64 + col],  bz_h = bhh[64 + col];
        float bn_i = bih[128 + col], bn_h = bhh[128 + col];
        #pragma unroll
        for (int r = 0; r < 4; ++r){
            int row = wv*16 + crow + r;
            float rg = sigf(gi[ct][r] + br_i + gh[ct][r] + br_h);
            float zg = sigf(gi[ct+4][r] + bz_i + gh[ct+4][r] + bz_h);
            float ng = tanhf(gi[ct+8][r] + bn_i + rg * (gh[ct+8][r] + bn_h));
            float h  = s_h[row * LDH + col];
            s_aux[row * LDH + col] = (1.f - zg) * ng + zg * h;
        }
    }
    __syncthreads();

    {
        int row = tid >> 2, cb = (tid & 3) * 16;
        #pragma unroll
        for (int q = 0; q < 4; ++q)
            *(float4*)(out + (size_t)(n0 + row) * DIM + cb + q*4) =
                *(const float4*)(s_aux + row * LDH + cb + q*4);
    }
}

// ---------------------------------------------------------------------------
// Fully fused Set2Set (3 steps) + final MLP. One block per graph.
// ---------------------------------------------------------------------------
__global__ __launch_bounds__(256) void k_s2s(
        const float* __restrict__ out, const int* __restrict__ batch,
        const float* __restrict__ wihT, const float* __restrict__ lbih,
        const float* __restrict__ whhT, const float* __restrict__ lbhh,
        const float* __restrict__ l1w, const float* __restrict__ l1b,
        const float* __restrict__ l2w, const float* __restrict__ l2b,
        float* __restrict__ y)
{
    __shared__ float s_q[128];
    __shared__ float s_hc[128];
    __shared__ float s_g[256];
    __shared__ float s_rw[256];
    __shared__ float s_sw[8];
    __shared__ int   s_rng[2];
    int g = blockIdx.x, tid = threadIdx.x;
    if (tid < 2){
        int target = g + tid;
        int lo = 0, hi = N_NODES;
        while (lo < hi){ int mid = (lo + hi) >> 1; if (batch[mid] < target) lo = mid + 1; else hi = mid; }
        s_rng[tid] = lo;
    }
    if (tid < 128){ s_q[tid] = 0.f; s_hc[tid] = 0.f; }
    __syncthreads();
    int s0 = s_rng[0], s1 = s_rng[1];
    int wv = tid >> 6, lane = tid & 63;

    for (int step = 0; step < 3; ++step){
        float acc = lbih[tid] + lbhh[tid];
        #pragma unroll 8
        for (int d = 0; d < 128; ++d) acc += s_q[d] * wihT[d * 256 + tid];
        #pragma unroll 8
        for (int d = 0; d < 64;  ++d) acc += s_hc[d] * whhT[d * 256 + tid];
        s_g[tid] = acc;
        __syncthreads();
        if (tid < 64){
            float c = sigf(s_g[64 + tid]) * s_hc[64 + tid] + sigf(s_g[tid]) * tanhf(s_g[128 + tid]);
            float h = sigf(s_g[192 + tid]) * tanhf(c);
            s_hc[tid] = h; s_hc[64 + tid] = c;
            s_q[tid] = h;
        }
        __syncthreads();
        float q = s_hc[lane];
        float emx = -3.4e38f;
        for (int n = s0 + wv; n < s1; n += 4){
            float v = out[(size_t)n * DIM + lane] * q;
            #pragma unroll
            for (int off = 32; off; off >>= 1) v += __shfl_xor(v, off);
            emx = fmaxf(emx, v);
        }
        if (lane == 0) s_sw[wv] = emx;
        __syncthreads();
        float gmax = fmaxf(fmaxf(s_sw[0], s_sw[1]), fmaxf(s_sw[2], s_sw[3]));
        float rl = 0.f, ss = 0.f;
        for (int n = s0 + wv; n < s1; n += 4){
            float o = out[(size_t)n * DIM + lane];
            float v = o * q;
            #pragma unroll
            for (int off = 32; off; off >>= 1) v += __shfl_xor(v, off);
            float ex = expf(v - gmax);
            rl += ex * o;
            ss += ex;
        }
        s_rw[wv * 64 + lane] = rl;
        if (lane == 0) s_sw[4 + wv] = ss;
        __syncthreads();
        if (tid < 64){
            float r = s_rw[tid] + s_rw[64 + tid] + s_rw[128 + tid] + s_rw[192 + tid];
            float S = fmaxf(s_sw[4] + s_sw[5] + s_sw[6] + s_sw[7], 1e-16f);
            s_q[64 + tid] = r / S;
        }
        __syncthreads();
    }
    if (wv == 0){
        float acc = l1b[lane];
        #pragma unroll 8
        for (int d = 0; d < 128; ++d) acc += s_q[d] * l1w[d * 64 + lane];
        float h = fmaxf(acc, 0.f);
        float p = h * l2w[lane];
        #pragma unroll
        for (int off = 32; off; off >>= 1) p += __shfl_down(p, off);
        if (lane == 0) y[g] = p + l2b[0];
    }
}

extern "C" void kernel_launch(void* const* d_in, const int* in_sizes, int n_in,
                              void* d_out, int out_size, void* d_ws, size_t ws_size,
                              hipStream_t stream){
    const float* x      = (const float*)d_in[0];
    const int*   ei     = (const int*)d_in[1];
    const float* ea     = (const float*)d_in[2];
    const int*   batch  = (const int*)d_in[3];
    const float* lin0_w = (const float*)d_in[6];
    const float* lin0_b = (const float*)d_in[7];
    const float* nn1_w  = (const float*)d_in[8];
    const float* nn1_b  = (const float*)d_in[9];
    const float* nn2_w  = (const float*)d_in[10];
    const float* nn2_b  = (const float*)d_in[11];
    const float* root_w = (const float*)d_in[12];
    const float* conv_b = (const float*)d_in[13];
    const float* gwih   = (const float*)d_in[14];
    const float* gwhh   = (const float*)d_in[15];
    const float* gbih   = (const float*)d_in[16];
    const float* gbhh   = (const float*)d_in[17];
    const float* lwih   = (const float*)d_in[18];
    const float* lwhh   = (const float*)d_in[19];
    const float* lbih   = (const float*)d_in[20];
    const float* lbhh   = (const float*)d_in[21];
    const float* l1w    = (const float*)d_in[22];
    const float* l1b    = (const float*)d_in[23];
    const float* l2w    = (const float*)d_in[24];
    const float* l2b    = (const float*)d_in[25];
    float* y = (float*)d_out;

    char* p = (char*)d_ws;
    float* out   = (float*)p;    p += (size_t)N_NODES * DIM * 4;
    float* agg   = (float*)p;    p += (size_t)N_NODES * DIM * 4;
    u16* w2T     = (u16*)p;      p += (size_t)EWCOLS * HIDN * 2;
    float* wihT  = (float*)p;    p += 128 * 256 * 4;
    float* whhT  = (float*)p;    p += 64 * 256 * 4;
    u16* rtHi    = (u16*)p;      p += 4096 * 2;
    u16* rtLo    = (u16*)p;      p += 4096 * 2;
    u16* wihHi   = (u16*)p;      p += 12288 * 2;
    u16* wihLo   = (u16*)p;      p += 12288 * 2;
    u16* whhHi   = (u16*)p;      p += 12288 * 2;
    u16* whhLo   = (u16*)p;      p += 12288 * 2;
    unsigned* degu = (unsigned*)p; p += N_NODES * 4;
    float* dinv  = (float*)p;    p += N_NODES * 4;

    if ((size_t)(p - (char*)d_ws) > ws_size) return;

    hipMemsetAsync(degu, 0, N_NODES * 4, stream);
    hipMemsetAsync(agg, 0, (size_t)N_NODES * DIM * 4, stream);  // k_update re-zeroes each round

    k_prep<<<2352, 256, 0, stream>>>(nn2_w, lwih, lwhh, root_w, gwih, gwhh,
                w2T, wihT, whhT, rtHi, rtLo, wihHi, wihLo, whhHi, whhLo);
    k_lin0<<<N_NODES / 4, 256, 0, stream>>>(x, lin0_w, lin0_b, out);
    k_deg <<<N_EDGES / 256, 256, 0, stream>>>(ei, degu);
    k_dinv<<<N_NODES / 256, 256, 0, stream>>>(degu, dinv);

    for (int r = 0; r < 3; ++r){
        k_msg_fused<<<N_EDGES / EB, 512, 0, stream>>>(ei, ea, nn1_w, nn1_b, w2T, nn2_b, out, agg);
        k_update   <<<N_NODES / 64, 256, 0, stream>>>(rtHi, rtLo, wihHi, wihLo, whhHi, whhLo,
                        conv_b, gbih, gbhh, agg, dinv, out);
    }

    k_s2s<<<NGRAPH, 256, 0, stream>>>(out, batch, wihT, lbih, whhT, lbhh,
                l1w, l1b, l2w, l2b, y);
}